// Round 2
// baseline (95.892 us; speedup 1.0000x reference)
//
#include <hip/hip_runtime.h>
#include <hip/hip_fp16.h>
#include <math.h>

// QFF1: per point n, per freq f: enc[m=s*3+d] = {sin,cos}(p_d * freq_f)
// pos = (enc+1)*39.5 ; lerp into table qv[f*6+m][cr][q]
// out[n][(f*2+s)*4 + c] = sum_r prod_d lerp(m=s*3+d, cr=c*8+r)
//
// LDS: fp16 tables, layout [m][q][40 halves] (32 data + 8 pad = 80 B rows).
// Row stride 80 B => 16B-chunk bank-group = (5q + jc) mod 8, 5 coprime 8 =>
// random rows spread over all 8 groups with no swizzle arithmetic, and the
// jc*16 chunk offset folds into the ds_read_b128 immediate.

constexpr int N_POINTS = 131072;
constexpr int NFREQ    = 6;
constexpr int QN       = 80;
constexpr int CRN      = 32;   // NUM_FEATS(4) * NUM_CORRS(8)
constexpr int M_PER_F  = 6;    // 2 (sin/cos) * 3 dims
constexpr int THREADS  = 512;
constexpr int ROW      = 40;           // halves per row (80 B)
constexpr int MSTRIDE  = QN * ROW;     // 3200 halves per table

__global__ __launch_bounds__(THREADS, 8)
void qff1_kernel(const float* __restrict__ points,
                 const float* __restrict__ qff,
                 const float* __restrict__ freqs,
                 float* __restrict__ out)
{
    __shared__ __align__(16) __half lds[M_PER_F * MSTRIDE];   // 38400 B -> 4 blocks/CU

    const int f = blockIdx.y;
    const float freq = freqs[f];

    // ---- stage fp16 tables, dst-linear so LDS writes are conflict-free b32;
    // global reads are scattered but L1/L2-resident (10 KB slice per m).
    const float* tab = qff + (size_t)f * (M_PER_F * CRN * QN);
    __half2* lds2 = reinterpret_cast<__half2*>(lds);
    for (int idx = threadIdx.x; idx < M_PER_F * QN * (CRN / 2); idx += THREADS) {
        int m   = idx / (QN * CRN / 2);
        int rem = idx - m * (QN * CRN / 2);
        int q   = rem >> 4;
        int cr2 = rem & 15;
        float v0 = tab[m * (CRN * QN) + (2 * cr2    ) * QN + q];
        float v1 = tab[m * (CRN * QN) + (2 * cr2 + 1) * QN + q];
        lds2[m * (MSTRIDE / 2) + q * (ROW / 2) + cr2] = __floats2half2_rn(v0, v1);
    }
    __syncthreads();

    const int n = blockIdx.x * THREADS + threadIdx.x;

    const float px = points[n * 3 + 0];
    const float py = points[n * 3 + 1];
    const float pz = points[n * 3 + 2];

    float enc[6];
    {
        float s, c;
        __sincosf(px * freq, &s, &c); enc[0] = s; enc[3] = c;
        __sincosf(py * freq, &s, &c); enc[1] = s; enc[4] = c;
        __sincosf(pz * freq, &s, &c); enc[2] = s; enc[5] = c;
    }

    int b0[6], b1[6];
    __half2 w2[6];
#pragma unroll
    for (int m = 0; m < 6; ++m) {
        float pos = (enc[m] + 1.0f) * 0.5f * (float)(QN - 1);
        float fi  = floorf(pos);
        int i0    = (int)fi;
        i0 = i0 < 0 ? 0 : (i0 > QN - 1 ? QN - 1 : i0);
        int i1 = i0 + 1; if (i1 > QN - 1) i1 = QN - 1;
        float w = pos - (float)i0;
        w2[m] = __float2half2_rn(w);
        b0[m] = m * MSTRIDE + i0 * ROW;
        b1[m] = m * MSTRIDE + i1 * ROW;
    }

    float acc[8];
#pragma unroll
    for (int k = 0; k < 8; ++k) acc[k] = 0.0f;

#pragma unroll
    for (int s = 0; s < 2; ++s) {
#pragma unroll
        for (int jc = 0; jc < 4; ++jc) {   // 16B chunk = 8 halves = one c (all 8 r)
            __half2 L[3][4];
#pragma unroll
            for (int d = 0; d < 3; ++d) {
                int m = s * 3 + d;
                union { float4 v; __half2 h[4]; } A, B;
                A.v = *(const float4*)&lds[b0[m] + jc * 8];
                B.v = *(const float4*)&lds[b1[m] + jc * 8];
#pragma unroll
                for (int k = 0; k < 4; ++k)
                    L[d][k] = __hfma2(w2[m], __hsub2(B.h[k], A.h[k]), A.h[k]);
            }
            float a = 0.0f;
#pragma unroll
            for (int k = 0; k < 4; ++k) {
                float2 f0 = __half22float2(L[0][k]);
                float2 f1 = __half22float2(L[1][k]);
                float2 f2 = __half22float2(L[2][k]);
                a += f0.x * f1.x * f2.x + f0.y * f1.y * f2.y;
            }
            acc[s * 4 + jc] = a;
        }
    }

    float4* o = (float4*)(out + (size_t)n * 48 + f * 8);
    o[0] = make_float4(acc[0], acc[1], acc[2], acc[3]);
    o[1] = make_float4(acc[4], acc[5], acc[6], acc[7]);
}

extern "C" void kernel_launch(void* const* d_in, const int* in_sizes, int n_in,
                              void* d_out, int out_size, void* d_ws, size_t ws_size,
                              hipStream_t stream) {
    const float* points = (const float*)d_in[0];   // (131072, 3)
    const float* qff    = (const float*)d_in[1];   // (36, 32, 80, 1)
    const float* freqs  = (const float*)d_in[2];   // (6,)
    float* out = (float*)d_out;                    // (131072, 48)

    dim3 grid(N_POINTS / THREADS, NFREQ);
    dim3 block(THREADS);
    qff1_kernel<<<grid, block, 0, stream>>>(points, qff, freqs, out);
}